// Round 10
// baseline (300.270 us; speedup 1.0000x reference)
//
#include <hip/hip_runtime.h>
#include <math.h>

#define ETA 1e-5f
#define MIN_SIGMA 1e-6f

constexpr int NN = 1024;  // N0 == N1
constexpr int ND = 128;   // D

// ws layout (floats)
constexpr size_t OFF_MAXKEY = 0;                       // u32[32] (fallback only)
constexpr size_t OFF_DEN    = 32;                      // f32[32]
constexpr size_t OFF_RW     = 64;                      // f32[32*1024]
constexpr size_t OFF_CW     = OFF_RW + 32 * 1024;      // f32[32*1024]
constexpr size_t OFF_X0N    = OFF_CW + 32 * 1024;      // f32[1024]
constexpr size_t OFF_X1N    = OFF_X0N + 1024;          // f32[1024]
constexpr size_t OFF_AP     = OFF_X1N + 1024;          // f32[32*1024]
constexpr size_t OFF_BP     = OFF_AP + 32 * 1024;      // f32[32*1024]
constexpr size_t OFF_C2     = OFF_BP + 32 * 1024;      // f32[32]
constexpr size_t OFF_QA     = ((OFF_C2 + 32 + 255) / 256) * 256;  // f32[1024*1024]
constexpr size_t OFF_DOT    = OFF_QA;                  // fallback alias
constexpr size_t OFF_PA     = OFF_QA + 1024 * 1024;    // f32[1024*1024]
constexpr size_t OFF_RA     = OFF_PA + 1024 * 1024;    // f32[1024*1024]
constexpr size_t OFF_RWP    = OFF_RA + 1024 * 1024;    // f32[32][32][1024]
constexpr size_t OFF_CWP    = OFF_RWP + 32 * 32 * 1024;// f32[32][32][1024]
constexpr size_t OFF_MLOC   = OFF_CWP + 32 * 32 * 1024;// f32[32][32][32]
constexpr size_t WS_NEED_NEW = OFF_MLOC + 32 * 32 * 32;
constexpr size_t WS_NEED_FALLBACK = OFF_DOT + 1024 * 1024;

__device__ __forceinline__ unsigned fkey(float x) {
  unsigned u = __float_as_uint(x);
  return (u & 0x80000000u) ? ~u : (u | 0x80000000u);
}
__device__ __forceinline__ float funkey(unsigned u) {
  return (u & 0x80000000u) ? __uint_as_float(u & 0x7fffffffu)
                           : __uint_as_float(~u);
}

// ---------------- k_ab: Ap[b,i], Bp[b,j], c2[b], x0n, x1n ----------------
// grid 1024: block = b*32 + strip(32 rows); 8 lanes per row, shfl-reduce.
__global__ __launch_bounds__(256) void k_ab(const float* __restrict__ xt,
                                            const float* __restrict__ tarr,
                                            const float* __restrict__ x0,
                                            const float* __restrict__ x1,
                                            float* __restrict__ ws) {
  __shared__ __align__(16) float xts[ND];
  int b = blockIdx.x >> 5, strip = blockIdx.x & 31;
  int tid = threadIdx.x;
  if (tid < ND) xts[tid] = xt[(size_t)b * ND + tid];
  __syncthreads();

  float tb = tarr[b];
  float omt = 1.f - tb;
  float ib2 = 1.f / ((tb + ETA) * (1.f - tb + ETA));

  int r = strip * 32 + (tid >> 3);
  int q8 = tid & 7;  // 16 dims each
  const float* xr = &xts[q8 * 16];
  const float* a0p = x0 + (size_t)r * ND + q8 * 16;
  const float* a1p = x1 + (size_t)r * ND + q8 * 16;
  float acc0 = 0.f, acc1 = 0.f, n0 = 0.f, n1 = 0.f, xtn = 0.f;
#pragma unroll
  for (int k4 = 0; k4 < 4; k4++) {
    float4 xv = *(const float4*)&xr[k4 * 4];
    float4 a = *(const float4*)&a0p[k4 * 4];
    float4 c = *(const float4*)&a1p[k4 * 4];
    acc0 += xv.x * a.x + xv.y * a.y + xv.z * a.z + xv.w * a.w;
    acc1 += xv.x * c.x + xv.y * c.y + xv.z * c.z + xv.w * c.w;
    n0 += a.x * a.x + a.y * a.y + a.z * a.z + a.w * a.w;
    n1 += c.x * c.x + c.y * c.y + c.z * c.z + c.w * c.w;
    xtn += xv.x * xv.x + xv.y * xv.y + xv.z * xv.z + xv.w * xv.w;
  }
#pragma unroll
  for (int off = 1; off < 8; off <<= 1) {
    acc0 += __shfl_xor(acc0, off, 64);
    acc1 += __shfl_xor(acc1, off, 64);
    n0 += __shfl_xor(n0, off, 64);
    n1 += __shfl_xor(n1, off, 64);
    xtn += __shfl_xor(xtn, off, 64);
  }
  if (q8 == 0) {
    ws[OFF_AP + (size_t)b * NN + r] =
        fmaf(omt * omt, n0, fmaf(-2.f * omt, acc0, xtn)) * ib2;
    ws[OFF_BP + (size_t)b * NN + r] =
        fmaf(tb * tb, n1, -2.f * tb * acc1) * ib2;
    if (b == 0) {
      ws[OFF_X0N + r] = n0;
      ws[OFF_X1N + r] = n1;
    }
  }
  if (strip == 0 && tid == 0) ws[OFF_C2 + b] = 2.f * tb * omt * ib2;
}

// ---------------- kG: GEMM + QPR store (grid 32x32) ----------------
__global__ __launch_bounds__(256) void kG(const float* __restrict__ x0,
                                          const float* __restrict__ x1,
                                          const float* __restrict__ sigw,
                                          float* __restrict__ ws) {
  __shared__ __align__(16) float As[32][36];
  __shared__ __align__(16) float Bs[32][36];
  __shared__ float x0nS[32], x1nS[32];

  int tid = threadIdx.x;
  int tx = tid & 15, ty = tid >> 4;
  int i0 = blockIdx.y * 32, j0 = blockIdx.x * 32;

  if (tid < 32) {
    x0nS[tid] = ws[OFF_X0N + i0 + tid];
    x1nS[tid] = ws[OFF_X1N + j0 + tid];
  }

  float c00 = 0.f, c01 = 0.f, c10 = 0.f, c11 = 0.f;
  int srow = tid >> 3, sk4 = tid & 7;
  for (int kc = 0; kc < 4; kc++) {
    __syncthreads();
    float4 a = *(const float4*)(x0 + (size_t)(i0 + srow) * ND + kc * 32 + sk4 * 4);
    float4 bb = *(const float4*)(x1 + (size_t)(j0 + srow) * ND + kc * 32 + sk4 * 4);
    As[sk4 * 4 + 0][srow] = a.x;
    As[sk4 * 4 + 1][srow] = a.y;
    As[sk4 * 4 + 2][srow] = a.z;
    As[sk4 * 4 + 3][srow] = a.w;
    Bs[sk4 * 4 + 0][srow] = bb.x;
    Bs[sk4 * 4 + 1][srow] = bb.y;
    Bs[sk4 * 4 + 2][srow] = bb.z;
    Bs[sk4 * 4 + 3][srow] = bb.w;
    __syncthreads();
#pragma unroll
    for (int k = 0; k < 32; k++) {
      float2 av = *(const float2*)&As[k][ty * 2];
      float2 bv = *(const float2*)&Bs[k][tx * 2];
      c00 = fmaf(av.x, bv.x, c00);
      c01 = fmaf(av.x, bv.y, c01);
      c10 = fmaf(av.y, bv.x, c10);
      c11 = fmaf(av.y, bv.y, c11);
    }
  }

  float swv = sigw[0];
  float sp = (swv > 20.f) ? swv : log1pf(__expf(swv));
  float dotv[2][2] = {{c00, c01}, {c10, c11}};
  float* QA = ws + OFF_QA;
  float* PA = ws + OFF_PA;
  float* RA = ws + OFF_RA;
#pragma unroll
  for (int r = 0; r < 2; r++) {
    float q2[2], p2[2], r2[2];
#pragma unroll
    for (int c = 0; c < 2; c++) {
      float d01 = x0nS[ty * 2 + r] + x1nS[tx * 2 + c] - 2.f * dotv[r][c];
      float ss = fmaf(sp, sqrtf(fmaxf(d01, 0.f) * (1.f / 128.f)), MIN_SIGMA);
      float Q = -0.72134752044f / (ss * ss);  // -log2e/2 / ss^2
      q2[c] = Q;
      p2[c] = dotv[r][c] * Q;
      r2[c] = -128.f * __log2f(ss);
    }
    size_t g = (size_t)(i0 + ty * 2 + r) * NN + j0 + tx * 2;
    *(float2*)&QA[g] = make_float2(q2[0], q2[1]);
    *(float2*)&PA[g] = make_float2(p2[0], p2[1]);
    *(float2*)&RA[g] = make_float2(r2[0], r2[1]);
  }
}

// ---------------- kE: softmax passes (grid 32x32x4, 8 b's per block) ----
// thread = (i = tid&31 owns row, b8 = tid>>5 owns one of 8 b's); loops j.
__global__ __launch_bounds__(256) void kE(float* __restrict__ ws) {
  __shared__ __align__(16) float QS[32][33], PS[32][33], RS[32][33];
  __shared__ float BpS[32][9], colS[32][9];
  __shared__ unsigned mS[8];

  int tid = threadIdx.x;
  int jb = blockIdx.x, ib = blockIdx.y, bq = blockIdx.z;
  int i0 = ib * 32, j0 = jb * 32;
  int i = tid & 31, b8 = tid >> 5;
  int b = bq * 8 + b8;

  // stage QPR tile (coalesced rows)
  {
    const float* QA = ws + OFF_QA;
    const float* PA = ws + OFF_PA;
    const float* RA = ws + OFF_RA;
#pragma unroll
    for (int rep = 0; rep < 4; rep++) {
      int idx = rep * 256 + tid;
      int r = idx >> 5, c = idx & 31;
      size_t g = (size_t)(i0 + r) * NN + j0 + c;
      QS[r][c] = QA[g];
      PS[r][c] = PA[g];
      RS[r][c] = RA[g];
    }
  }
  {
    int j = tid & 31, bb = tid >> 5;
    BpS[j][bb] = ws[OFF_BP + (size_t)(bq * 8 + bb) * NN + j0 + j];
    colS[j][bb] = 0.f;
  }
  if (tid < 8) mS[tid] = 0u;
  float ap = ws[OFF_AP + (size_t)b * NN + i0 + i];
  float c2b = ws[OFF_C2 + b];
  __syncthreads();

  // pass A: tile-local max for (b); skewed j -> conflict-free LDS
  float m = -3.4e38f;
#pragma unroll
  for (int jj = 0; jj < 32; jj++) {
    int j = (jj + i) & 31;
    float core = fmaf(ap + BpS[j][b8], QS[i][j], fmaf(c2b, PS[i][j], RS[i][j]));
    m = fmaxf(m, core);
  }
  atomicMax(&mS[b8], fkey(m));
  __syncthreads();
  float m2 = funkey(mS[b8]);

  // pass B: exp2 vs local max; row sum private, col sums via skewed LDS atomics
  float rs = 0.f;
#pragma unroll
  for (int jj = 0; jj < 32; jj++) {
    int j = (jj + i) & 31;
    float core = fmaf(ap + BpS[j][b8], QS[i][j], fmaf(c2b, PS[i][j], RS[i][j]));
    float w = exp2f(core - m2);
    rs += w;
    atomicAdd(&colS[j][b8], w);
  }
  // row partial: unique writer -> direct global store (coalesced over i)
  ws[OFF_RWP + (size_t)jb * (32 * 1024) + (size_t)b * NN + i0 + i] = rs;
  __syncthreads();
  {
    int j = tid & 31, bb = tid >> 5;
    ws[OFF_CWP + (size_t)ib * (32 * 1024) + (size_t)(bq * 8 + bb) * NN + j0 + j] =
        colS[j][bb];
  }
  if (tid < 8)
    ws[OFF_MLOC + ((size_t)ib * 32 + jb) * 32 + bq * 8 + tid] = funkey(mS[tid]);
}

// ---------------- kR: rescale-merge partials into rw/cw + den --------
__global__ __launch_bounds__(256) void kR(float* __restrict__ ws) {
  __shared__ float red[256];
  int b = blockIdx.x >> 2, quarter = blockIdx.x & 3;
  int tid = threadIdx.x;

  const float* ml = ws + OFF_MLOC + b;
  float mx = -3.4e38f;
#pragma unroll
  for (int k = 0; k < 4; k++) mx = fmaxf(mx, ml[(size_t)(k * 256 + tid) * 32]);
  red[tid] = mx;
  __syncthreads();
  for (int s = 128; s > 0; s >>= 1) {
    if (tid < s) red[tid] = fmaxf(red[tid], red[tid + s]);
    __syncthreads();
  }
  float mg = red[0];
  __syncthreads();

  int i = quarter * 256 + tid;
  int tb = i >> 5;
  const float* rwp = ws + OFF_RWP + (size_t)b * NN + i;
  const float* cwp = ws + OFF_CWP + (size_t)b * NN + i;
  const float* mlI = ws + OFF_MLOC + (size_t)tb * 1024 + b;
  const float* mlJ = ws + OFF_MLOC + (size_t)tb * 32 + b;
  float s0 = 0.f, s1 = 0.f;
#pragma unroll 8
  for (int p = 0; p < 32; p++) {
    s0 = fmaf(exp2f(mlI[(size_t)p * 32] - mg), rwp[(size_t)p * 32 * 1024], s0);
    s1 = fmaf(exp2f(mlJ[(size_t)p * 1024] - mg), cwp[(size_t)p * 32 * 1024], s1);
  }
  ws[OFF_RW + (size_t)b * NN + i] = s0;
  ws[OFF_CW + (size_t)b * NN + i] = s1;

  red[tid] = s0;
  __syncthreads();
  for (int s = 128; s > 0; s >>= 1) {
    if (tid < s) red[tid] += red[tid + s];
    __syncthreads();
  }
  if (tid == 0) atomicAdd(ws + OFF_DEN + b, red[0]);
}

// ---------------- fallback path (round-3 proven): k1 + k2 atomic -----
__global__ __launch_bounds__(256) void k1(const float* __restrict__ x0,
                                          const float* __restrict__ x1,
                                          const float* __restrict__ sigw,
                                          float* __restrict__ ws) {
  __shared__ __align__(16) float As[32][36];
  __shared__ __align__(16) float Bs[32][36];
  __shared__ __align__(16) float4 QPRS[32][32];
  __shared__ float ApT[32][33], BpT[32][33];
  __shared__ float x0nS[32], x1nS[32];
  __shared__ unsigned mS[32];

  int tid = threadIdx.x;
  int tx = tid & 15, ty = tid >> 4;
  int i0 = blockIdx.y * 32, j0 = blockIdx.x * 32;

  {
    const float* Ap = ws + OFF_AP;
    const float* Bp = ws + OFF_BP;
#pragma unroll
    for (int rep = 0; rep < 4; rep++) {
      int idx = rep * 256 + tid;
      int bb = idx >> 5, ii = idx & 31;
      ApT[ii][bb] = Ap[(size_t)bb * NN + i0 + ii];
      BpT[ii][bb] = Bp[(size_t)bb * NN + j0 + ii];
    }
    if (tid < 32) {
      x0nS[tid] = ws[OFF_X0N + i0 + tid];
      x1nS[tid] = ws[OFF_X1N + j0 + tid];
      mS[tid] = 0u;
    }
  }

  float c00 = 0.f, c01 = 0.f, c10 = 0.f, c11 = 0.f;
  int srow = tid >> 3, sk4 = tid & 7;
  for (int kc = 0; kc < 4; kc++) {
    __syncthreads();
    float4 a = *(const float4*)(x0 + (size_t)(i0 + srow) * ND + kc * 32 + sk4 * 4);
    float4 bb = *(const float4*)(x1 + (size_t)(j0 + srow) * ND + kc * 32 + sk4 * 4);
    As[sk4 * 4 + 0][srow] = a.x;
    As[sk4 * 4 + 1][srow] = a.y;
    As[sk4 * 4 + 2][srow] = a.z;
    As[sk4 * 4 + 3][srow] = a.w;
    Bs[sk4 * 4 + 0][srow] = bb.x;
    Bs[sk4 * 4 + 1][srow] = bb.y;
    Bs[sk4 * 4 + 2][srow] = bb.z;
    Bs[sk4 * 4 + 3][srow] = bb.w;
    __syncthreads();
#pragma unroll
    for (int k = 0; k < 32; k++) {
      float2 av = *(const float2*)&As[k][ty * 2];
      float2 bv = *(const float2*)&Bs[k][tx * 2];
      c00 = fmaf(av.x, bv.x, c00);
      c01 = fmaf(av.x, bv.y, c01);
      c10 = fmaf(av.y, bv.x, c10);
      c11 = fmaf(av.y, bv.y, c11);
    }
  }

  float* dot = ws + OFF_DOT;
  *(float2*)&dot[(size_t)(i0 + ty * 2 + 0) * NN + j0 + tx * 2] = make_float2(c00, c01);
  *(float2*)&dot[(size_t)(i0 + ty * 2 + 1) * NN + j0 + tx * 2] = make_float2(c10, c11);

  float swv = sigw[0];
  float sp = (swv > 20.f) ? swv : log1pf(__expf(swv));
  float dotv[2][2] = {{c00, c01}, {c10, c11}};
#pragma unroll
  for (int r = 0; r < 2; r++) {
#pragma unroll
    for (int c = 0; c < 2; c++) {
      float d01 = x0nS[ty * 2 + r] + x1nS[tx * 2 + c] - 2.f * dotv[r][c];
      float ss = fmaf(sp, sqrtf(fmaxf(d01, 0.f) * (1.f / 128.f)), MIN_SIGMA);
      float Q = -0.72134752044f / (ss * ss);
      float R = -128.f * __log2f(ss);
      QPRS[ty * 2 + r][tx * 2 + c] = make_float4(Q, dotv[r][c] * Q, R, 0.f);
    }
  }
  __syncthreads();

  int b = tid & 31, rep = tid >> 5;
  float c2b = ws[OFF_C2 + b];
  float bpreg[32];
#pragma unroll
  for (int j = 0; j < 32; j++) bpreg[j] = BpT[j][b];
  float m = -3.4e38f;
#pragma unroll
  for (int r = 0; r < 4; r++) {
    int i = rep * 4 + r;
    float ap = ApT[i][b];
#pragma unroll
    for (int j = 0; j < 32; j++) {
      float4 q4 = QPRS[i][j];
      float core = fmaf(ap + bpreg[j], q4.x, fmaf(c2b, q4.y, q4.z));
      m = fmaxf(m, core);
    }
  }
  atomicMax(&mS[b], fkey(m));
  __syncthreads();
  if (tid < 32) atomicMax((unsigned*)ws + OFF_MAXKEY + tid, mS[tid]);
}

__global__ __launch_bounds__(256) void k2(const float* __restrict__ sigw,
                                          float* __restrict__ ws) {
  __shared__ __align__(16) float4 QPRS[32][32];
  __shared__ float ApT[32][33], BpT[32][33];
  __shared__ float colS[32][33], rowS[32][33];
  __shared__ float x0nS[32], x1nS[32];
  __shared__ float denS[32];

  int tid = threadIdx.x;
  int tx = tid & 15, ty = tid >> 4;
  int i0 = blockIdx.y * 32, j0 = blockIdx.x * 32;

  {
    const float* Ap = ws + OFF_AP;
    const float* Bp = ws + OFF_BP;
#pragma unroll
    for (int rep = 0; rep < 4; rep++) {
      int idx = rep * 256 + tid;
      int bb = idx >> 5, ii = idx & 31;
      ApT[ii][bb] = Ap[(size_t)bb * NN + i0 + ii];
      BpT[ii][bb] = Bp[(size_t)bb * NN + j0 + ii];
      colS[ii][bb] = 0.f;
    }
    if (tid < 32) {
      x0nS[tid] = ws[OFF_X0N + i0 + tid];
      x1nS[tid] = ws[OFF_X1N + j0 + tid];
      denS[tid] = 0.f;
    }
  }

  const float* dot = ws + OFF_DOT;
  float2 dv0 = *(const float2*)&dot[(size_t)(i0 + ty * 2 + 0) * NN + j0 + tx * 2];
  float2 dv1 = *(const float2*)&dot[(size_t)(i0 + ty * 2 + 1) * NN + j0 + tx * 2];
  float dotv[2][2] = {{dv0.x, dv0.y}, {dv1.x, dv1.y}};
  float swv = sigw[0];
  float sp = (swv > 20.f) ? swv : log1pf(__expf(swv));

  __syncthreads();

#pragma unroll
  for (int r = 0; r < 2; r++) {
#pragma unroll
    for (int c = 0; c < 2; c++) {
      float d01 = x0nS[ty * 2 + r] + x1nS[tx * 2 + c] - 2.f * dotv[r][c];
      float ss = fmaf(sp, sqrtf(fmaxf(d01, 0.f) * (1.f / 128.f)), MIN_SIGMA);
      float Q = -0.72134752044f / (ss * ss);
      float R = -128.f * __log2f(ss);
      QPRS[ty * 2 + r][tx * 2 + c] = make_float4(Q, dotv[r][c] * Q, R, 0.f);
    }
  }
  __syncthreads();

  int b = tid & 31, rep = tid >> 5;
  float c2b = ws[OFF_C2 + b];
  float m2 = funkey(((const unsigned*)ws)[OFF_MAXKEY + b]);
  float bpreg[32];
#pragma unroll
  for (int j = 0; j < 32; j++) bpreg[j] = BpT[j][b];
  float colreg[32];
#pragma unroll
  for (int j = 0; j < 32; j++) colreg[j] = 0.f;
  float dreg = 0.f;
#pragma unroll
  for (int r = 0; r < 4; r++) {
    int i = rep * 4 + r;
    float ap = ApT[i][b];
    float rs = 0.f;
#pragma unroll
    for (int j = 0; j < 32; j++) {
      float4 q4 = QPRS[i][j];
      float core = fmaf(ap + bpreg[j], q4.x, fmaf(c2b, q4.y, q4.z));
      float w = exp2f(core - m2);
      rs += w;
      colreg[j] += w;
    }
    rowS[i][b] = rs;
    dreg += rs;
  }
#pragma unroll
  for (int j = 0; j < 32; j++) atomicAdd(&colS[j][b], colreg[j]);
  atomicAdd(&denS[b], dreg);
  __syncthreads();

  float* rw = ws + OFF_RW;
  float* cw = ws + OFF_CW;
#pragma unroll
  for (int k = 0; k < 4; k++) {
    int idx = k * 256 + tid;
    int bb = idx >> 5, ii = idx & 31;
    atomicAdd(&rw[(size_t)bb * NN + i0 + ii], rowS[ii][bb]);
    atomicAdd(&cw[(size_t)bb * NN + j0 + ii], colS[ii][bb]);
  }
  if (tid < 32) atomicAdd(ws + OFF_DEN + tid, denS[tid]);
}

// ---------------- k3: weighted combine (grid 512 = b x 16 strips) ----
__global__ __launch_bounds__(256) void k3(const float* __restrict__ xt,
                                          const float* __restrict__ tarr,
                                          const float* __restrict__ x0,
                                          const float* __restrict__ x1,
                                          const float* __restrict__ ws,
                                          float* __restrict__ out) {
  __shared__ float s0[32][8], s1[32][8];
  int b = blockIdx.x >> 4, strip = blockIdx.x & 15;
  int tid = threadIdx.x;
  int c = tid & 7, h = tid >> 3;  // h in 0..31, 32 rows each
  int d = strip * 8 + c;
  const float* rw = ws + OFF_RW + (size_t)b * NN;
  const float* cw = ws + OFF_CW + (size_t)b * NN;
  float a0 = 0.f, a1 = 0.f;
#pragma unroll 4
  for (int k = 0; k < 32; k++) {
    int i = h * 32 + k;
    a0 = fmaf(rw[i], x0[(size_t)i * ND + d], a0);
    a1 = fmaf(cw[i], x1[(size_t)i * ND + d], a1);
  }
  s0[h][c] = a0;
  s1[h][c] = a1;
  __syncthreads();
  for (int s = 16; s > 0; s >>= 1) {
    if (h < s) {
      s0[h][c] += s0[h + s][c];
      s1[h][c] += s1[h + s][c];
    }
    __syncthreads();
  }
  if (h == 0) {
    float tb = tarr[b];
    float den = ws[OFF_DEN + b];
    float ct = (1.f - 2.f * tb) / (2.f * (tb + ETA) * (1.f - tb + ETA));
    float av = -1.f - ct * (1.f - tb);
    float bv = 1.f - ct * tb;
    float den_c = fmaxf(den, 1e-12f);
    out[(size_t)b * ND + d] =
        (ct * xt[(size_t)b * ND + d] * den + av * s0[0][c] + bv * s1[0][c]) / den_c;
  }
}

extern "C" void kernel_launch(void* const* d_in, const int* in_sizes, int n_in,
                              void* d_out, int out_size, void* d_ws, size_t ws_size,
                              hipStream_t stream) {
  const float* xt = (const float*)d_in[0];
  const float* t = (const float*)d_in[1];
  const float* x0 = (const float*)d_in[2];
  const float* x1 = (const float*)d_in[3];
  const float* sw = (const float*)d_in[4];
  float* out = (float*)d_out;
  float* ws = (float*)d_ws;

  bool newpath = ws_size >= WS_NEED_NEW * sizeof(float);

  if (newpath) {
    hipMemsetAsync(ws, 0, 64 * sizeof(float), stream);  // maxkey+den
    k_ab<<<1024, 256, 0, stream>>>(xt, t, x0, x1, ws);
    kG<<<dim3(32, 32), 256, 0, stream>>>(x0, x1, sw, ws);
    kE<<<dim3(32, 32, 4), 256, 0, stream>>>(ws);
    kR<<<128, 256, 0, stream>>>(ws);
  } else {
    hipMemsetAsync(ws, 0, OFF_X0N * sizeof(float), stream);
    k_ab<<<1024, 256, 0, stream>>>(xt, t, x0, x1, ws);
    k1<<<dim3(32, 32), 256, 0, stream>>>(x0, x1, sw, ws);
    k2<<<dim3(32, 32), 256, 0, stream>>>(sw, ws);
  }
  k3<<<512, 256, 0, stream>>>(xt, t, x0, x1, ws, out);
}

// Round 11
// 151.798 us; speedup vs baseline: 1.9781x; 1.9781x over previous
//
#include <hip/hip_runtime.h>
#include <math.h>

#define ETA 1e-5f
#define MIN_SIGMA 1e-6f

constexpr int NN = 1024;  // N0 == N1
constexpr int ND = 128;   // D

// ws layout (floats) -- round-9 fused layout
constexpr size_t OFF_MAXKEY = 0;                       // u32[32] (fallback only)
constexpr size_t OFF_DEN    = 32;                      // f32[32]
constexpr size_t OFF_RW     = 64;                      // f32[32*1024]
constexpr size_t OFF_CW     = OFF_RW + 32 * 1024;      // f32[32*1024]
constexpr size_t OFF_X0N    = OFF_CW + 32 * 1024;      // f32[1024]
constexpr size_t OFF_X1N    = OFF_X0N + 1024;          // f32[1024]
constexpr size_t OFF_AP     = OFF_X1N + 1024;          // f32[32*1024]
constexpr size_t OFF_BP     = OFF_AP + 32 * 1024;      // f32[32*1024]
constexpr size_t OFF_C2     = OFF_BP + 32 * 1024;      // f32[32]
constexpr size_t OFF_RWP    = ((OFF_C2 + 32 + 63) / 64) * 64;  // f32[32][32][1024]
constexpr size_t OFF_DOT    = OFF_RWP;                 // fallback alias
constexpr size_t OFF_CWP    = OFF_RWP + 32 * 32 * 1024;// f32[32][32][1024]
constexpr size_t OFF_MLOC   = OFF_CWP + 32 * 32 * 1024;// f32[32][32][32]
constexpr size_t WS_NEED_FUSED = OFF_MLOC + 32 * 32 * 32;

__device__ __forceinline__ unsigned fkey(float x) {
  unsigned u = __float_as_uint(x);
  return (u & 0x80000000u) ? ~u : (u | 0x80000000u);
}
__device__ __forceinline__ float funkey(unsigned u) {
  return (u & 0x80000000u) ? __uint_as_float(u & 0x7fffffffu)
                           : __uint_as_float(~u);
}

// ---------------- k_ab (grid 1024): Ap, Bp, c2, x0n, x1n ----------------
__global__ __launch_bounds__(256) void k_ab(const float* __restrict__ xt,
                                            const float* __restrict__ tarr,
                                            const float* __restrict__ x0,
                                            const float* __restrict__ x1,
                                            float* __restrict__ ws) {
  __shared__ __align__(16) float xts[ND];
  int b = blockIdx.x >> 5, strip = blockIdx.x & 31;
  int tid = threadIdx.x;
  if (tid < ND) xts[tid] = xt[(size_t)b * ND + tid];
  __syncthreads();

  float tb = tarr[b];
  float omt = 1.f - tb;
  float ib2 = 1.f / ((tb + ETA) * (1.f - tb + ETA));

  int r = strip * 32 + (tid >> 3);
  int q8 = tid & 7;  // 16 dims each
  const float* xr = &xts[q8 * 16];
  const float* a0p = x0 + (size_t)r * ND + q8 * 16;
  const float* a1p = x1 + (size_t)r * ND + q8 * 16;
  float acc0 = 0.f, acc1 = 0.f, n0 = 0.f, n1 = 0.f, xtn = 0.f;
#pragma unroll
  for (int k4 = 0; k4 < 4; k4++) {
    float4 xv = *(const float4*)&xr[k4 * 4];
    float4 a = *(const float4*)&a0p[k4 * 4];
    float4 c = *(const float4*)&a1p[k4 * 4];
    acc0 += xv.x * a.x + xv.y * a.y + xv.z * a.z + xv.w * a.w;
    acc1 += xv.x * c.x + xv.y * c.y + xv.z * c.z + xv.w * c.w;
    n0 += a.x * a.x + a.y * a.y + a.z * a.z + a.w * a.w;
    n1 += c.x * c.x + c.y * c.y + c.z * c.z + c.w * c.w;
    xtn += xv.x * xv.x + xv.y * xv.y + xv.z * xv.z + xv.w * xv.w;
  }
#pragma unroll
  for (int off = 1; off < 8; off <<= 1) {
    acc0 += __shfl_xor(acc0, off, 64);
    acc1 += __shfl_xor(acc1, off, 64);
    n0 += __shfl_xor(n0, off, 64);
    n1 += __shfl_xor(n1, off, 64);
    xtn += __shfl_xor(xtn, off, 64);
  }
  if (q8 == 0) {
    ws[OFF_AP + (size_t)b * NN + r] =
        fmaf(omt * omt, n0, fmaf(-2.f * omt, acc0, xtn)) * ib2;
    ws[OFF_BP + (size_t)b * NN + r] =
        fmaf(tb * tb, n1, -2.f * tb * acc1) * ib2;
    if (b == 0) {
      ws[OFF_X0N + r] = n0;
      ws[OFF_X1N + r] = n1;
    }
  }
  if (strip == 0 && tid == 0) ws[OFF_C2 + b] = 2.f * tb * omt * ib2;
}

// ---------------- kF: 512-thread fused GEMM + QPR + passes ----------------
// GEMM: waves 0-3 stage A, waves 4-7 stage B; thread (gi=tid>>4, gtx=tid&15)
// computes 1x2 outputs. Passes: thread (b=tid>>4, jg=tid&15) owns 2 cols;
// 16 jg-threads per b are consecutive lanes -> shfl row-reduce, all unique
// writers (no LDS atomics at all).
__global__ __launch_bounds__(512, 8) void kF(const float* __restrict__ x0,
                                             const float* __restrict__ x1,
                                             const float* __restrict__ sigw,
                                             float* __restrict__ ws) {
  __shared__ __align__(16) float gemmbuf[2304];  // As/Bs, then rowP/colS
  __shared__ __align__(16) float4 QPRS[32][32];
  __shared__ float ApT[32][33], BpT[32][33];
  __shared__ float x0nS[32], x1nS[32];
  __shared__ float mS[32];

  float (*As)[36] = (float(*)[36])&gemmbuf[0];
  float (*Bs)[36] = (float(*)[36])&gemmbuf[1152];
  float (*rowP)[33] = (float(*)[33])&gemmbuf[0];     // [32][33]
  float (*colS)[33] = (float(*)[33])&gemmbuf[1056];  // [32][33]

  int tid = threadIdx.x;
  int jb = blockIdx.x, ib = blockIdx.y;
  int i0 = ib * 32, j0 = jb * 32;

  {
    const float* Ap = ws + OFF_AP;
    const float* Bp = ws + OFF_BP;
#pragma unroll
    for (int rep = 0; rep < 2; rep++) {
      int idx = rep * 512 + tid;
      int bb = idx >> 5, ii = idx & 31;
      ApT[ii][bb] = Ap[(size_t)bb * NN + i0 + ii];
      BpT[ii][bb] = Bp[(size_t)bb * NN + j0 + ii];
    }
    if (tid < 32) {
      x0nS[tid] = ws[OFF_X0N + i0 + tid];
      x1nS[tid] = ws[OFF_X1N + j0 + tid];
    }
  }

  // GEMM 32x32x128, 1x2 outputs per thread
  int gi = tid >> 4, gtx = tid & 15;
  int half = tid >> 8;       // 0: stage A, 1: stage B (wave-uniform)
  int t = tid & 255;
  int srow = t >> 3, sk4 = t & 7;
  const float* src = half ? x1 : x0;
  int sbase = half ? j0 : i0;
  float c0 = 0.f, c1 = 0.f;
  for (int kc = 0; kc < 4; kc++) {
    __syncthreads();
    float4 a = *(const float4*)(src + (size_t)(sbase + srow) * ND + kc * 32 + sk4 * 4);
    float(*dst)[36] = half ? Bs : As;
    dst[sk4 * 4 + 0][srow] = a.x;
    dst[sk4 * 4 + 1][srow] = a.y;
    dst[sk4 * 4 + 2][srow] = a.z;
    dst[sk4 * 4 + 3][srow] = a.w;
    __syncthreads();
#pragma unroll
    for (int k = 0; k < 32; k++) {
      float av = As[k][gi];
      float2 bv = *(const float2*)&Bs[k][gtx * 2];
      c0 = fmaf(av, bv.x, c0);
      c1 = fmaf(av, bv.y, c1);
    }
  }

  // QPR (log2 domain), written by the same thread that computed the dots
  float swv = sigw[0];
  float sp = (swv > 20.f) ? swv : log1pf(__expf(swv));
  {
    float xn0 = x0nS[gi];
    float d0 = xn0 + x1nS[gtx * 2 + 0] - 2.f * c0;
    float d1 = xn0 + x1nS[gtx * 2 + 1] - 2.f * c1;
    float ss0 = fmaf(sp, sqrtf(fmaxf(d0, 0.f) * (1.f / 128.f)), MIN_SIGMA);
    float ss1 = fmaf(sp, sqrtf(fmaxf(d1, 0.f) * (1.f / 128.f)), MIN_SIGMA);
    float Q0 = -0.72134752044f / (ss0 * ss0);
    float Q1 = -0.72134752044f / (ss1 * ss1);
    QPRS[gi][gtx * 2 + 0] = make_float4(Q0, c0 * Q0, -128.f * __log2f(ss0), 0.f);
    QPRS[gi][gtx * 2 + 1] = make_float4(Q1, c1 * Q1, -128.f * __log2f(ss1), 0.f);
  }
  __syncthreads();  // QPRS ready; GEMM reads of As/Bs complete

  // pass A: local max; (b, jg) layout, shfl-reduce over the 16 jg lanes
  int b = tid >> 4, jg = tid & 15;
  float c2b = ws[OFF_C2 + b];
  float bp0 = BpT[jg * 2 + 0][b];
  float bp1 = BpT[jg * 2 + 1][b];
  float m = -3.4e38f;
#pragma unroll
  for (int i = 0; i < 32; i++) {
    float ap = ApT[i][b];
    float4 q0 = QPRS[i][jg * 2 + 0];
    float4 q1 = QPRS[i][jg * 2 + 1];
    float core0 = fmaf(ap + bp0, q0.x, fmaf(c2b, q0.y, q0.z));
    float core1 = fmaf(ap + bp1, q1.x, fmaf(c2b, q1.y, q1.z));
    m = fmaxf(m, fmaxf(core0, core1));
  }
#pragma unroll
  for (int off = 1; off < 16; off <<= 1) m = fmaxf(m, __shfl_xor(m, off, 16));
  if (jg == 0) mS[b] = m;  // unique writer
  __syncthreads();

  // pass B: exp2 vs local max; rows shfl-reduced (unique store), cols private
  float m2 = mS[b];
  float cs0 = 0.f, cs1 = 0.f;
#pragma unroll
  for (int i = 0; i < 32; i++) {
    float ap = ApT[i][b];
    float4 q0 = QPRS[i][jg * 2 + 0];
    float4 q1 = QPRS[i][jg * 2 + 1];
    float w0 = exp2f(fmaf(ap + bp0, q0.x, fmaf(c2b, q0.y, q0.z)) - m2);
    float w1 = exp2f(fmaf(ap + bp1, q1.x, fmaf(c2b, q1.y, q1.z)) - m2);
    cs0 += w0;
    cs1 += w1;
    float rs = w0 + w1;
#pragma unroll
    for (int off = 1; off < 16; off <<= 1) rs += __shfl_xor(rs, off, 16);
    if (jg == 0) rowP[i][b] = rs;  // unique writer (gemmbuf overlay, GEMM done)
  }
  colS[jg * 2 + 0][b] = cs0;  // unique writer
  colS[jg * 2 + 1][b] = cs1;
  __syncthreads();

  // flush partials (plain coalesced stores)
  float* rwp = ws + OFF_RWP + (size_t)jb * (32 * 1024);  // [jb][b][i]
  float* cwp = ws + OFF_CWP + (size_t)ib * (32 * 1024);  // [ib][b][j]
#pragma unroll
  for (int rep = 0; rep < 2; rep++) {
    int idx = rep * 512 + tid;
    int bb = idx >> 5, ii = idx & 31;
    rwp[(size_t)bb * NN + i0 + ii] = rowP[ii][bb];
    cwp[(size_t)bb * NN + j0 + ii] = colS[ii][bb];
  }
  if (tid < 32) ws[OFF_MLOC + ((size_t)ib * 32 + jb) * 32 + tid] = mS[tid];
}

// ---------------- kR: rescale-merge partials into rw/cw + den --------
__global__ __launch_bounds__(256) void kR(float* __restrict__ ws) {
  __shared__ float red[256];
  int b = blockIdx.x >> 2, quarter = blockIdx.x & 3;
  int tid = threadIdx.x;

  const float* ml = ws + OFF_MLOC + b;
  float mx = -3.4e38f;
#pragma unroll
  for (int k = 0; k < 4; k++) mx = fmaxf(mx, ml[(size_t)(k * 256 + tid) * 32]);
  red[tid] = mx;
  __syncthreads();
  for (int s = 128; s > 0; s >>= 1) {
    if (tid < s) red[tid] = fmaxf(red[tid], red[tid + s]);
    __syncthreads();
  }
  float mg = red[0];
  __syncthreads();

  int i = quarter * 256 + tid;
  int tb = i >> 5;
  const float* rwp = ws + OFF_RWP + (size_t)b * NN + i;
  const float* cwp = ws + OFF_CWP + (size_t)b * NN + i;
  const float* mlI = ws + OFF_MLOC + (size_t)tb * 1024 + b;
  const float* mlJ = ws + OFF_MLOC + (size_t)tb * 32 + b;
  float s0 = 0.f, s1 = 0.f;
#pragma unroll 8
  for (int p = 0; p < 32; p++) {
    s0 = fmaf(exp2f(mlI[(size_t)p * 32] - mg), rwp[(size_t)p * 32 * 1024], s0);
    s1 = fmaf(exp2f(mlJ[(size_t)p * 1024] - mg), cwp[(size_t)p * 32 * 1024], s1);
  }
  ws[OFF_RW + (size_t)b * NN + i] = s0;
  ws[OFF_CW + (size_t)b * NN + i] = s1;

  red[tid] = s0;
  __syncthreads();
  for (int s = 128; s > 0; s >>= 1) {
    if (tid < s) red[tid] += red[tid + s];
    __syncthreads();
  }
  if (tid == 0) atomicAdd(ws + OFF_DEN + b, red[0]);
}

// ---------------- fallback path (round-3 proven): k1 + k2 atomic -----
__global__ __launch_bounds__(256) void k1(const float* __restrict__ x0,
                                          const float* __restrict__ x1,
                                          const float* __restrict__ sigw,
                                          float* __restrict__ ws) {
  __shared__ __align__(16) float As[32][36];
  __shared__ __align__(16) float Bs[32][36];
  __shared__ __align__(16) float4 QPRS[32][32];
  __shared__ float ApT[32][33], BpT[32][33];
  __shared__ float x0nS[32], x1nS[32];
  __shared__ unsigned mS[32];

  int tid = threadIdx.x;
  int tx = tid & 15, ty = tid >> 4;
  int i0 = blockIdx.y * 32, j0 = blockIdx.x * 32;

  {
    const float* Ap = ws + OFF_AP;
    const float* Bp = ws + OFF_BP;
#pragma unroll
    for (int rep = 0; rep < 4; rep++) {
      int idx = rep * 256 + tid;
      int bb = idx >> 5, ii = idx & 31;
      ApT[ii][bb] = Ap[(size_t)bb * NN + i0 + ii];
      BpT[ii][bb] = Bp[(size_t)bb * NN + j0 + ii];
    }
    if (tid < 32) {
      x0nS[tid] = ws[OFF_X0N + i0 + tid];
      x1nS[tid] = ws[OFF_X1N + j0 + tid];
      mS[tid] = 0u;
    }
  }

  float c00 = 0.f, c01 = 0.f, c10 = 0.f, c11 = 0.f;
  int srow = tid >> 3, sk4 = tid & 7;
  for (int kc = 0; kc < 4; kc++) {
    __syncthreads();
    float4 a = *(const float4*)(x0 + (size_t)(i0 + srow) * ND + kc * 32 + sk4 * 4);
    float4 bb = *(const float4*)(x1 + (size_t)(j0 + srow) * ND + kc * 32 + sk4 * 4);
    As[sk4 * 4 + 0][srow] = a.x;
    As[sk4 * 4 + 1][srow] = a.y;
    As[sk4 * 4 + 2][srow] = a.z;
    As[sk4 * 4 + 3][srow] = a.w;
    Bs[sk4 * 4 + 0][srow] = bb.x;
    Bs[sk4 * 4 + 1][srow] = bb.y;
    Bs[sk4 * 4 + 2][srow] = bb.z;
    Bs[sk4 * 4 + 3][srow] = bb.w;
    __syncthreads();
#pragma unroll
    for (int k = 0; k < 32; k++) {
      float2 av = *(const float2*)&As[k][ty * 2];
      float2 bv = *(const float2*)&Bs[k][tx * 2];
      c00 = fmaf(av.x, bv.x, c00);
      c01 = fmaf(av.x, bv.y, c01);
      c10 = fmaf(av.y, bv.x, c10);
      c11 = fmaf(av.y, bv.y, c11);
    }
  }

  float* dot = ws + OFF_DOT;
  *(float2*)&dot[(size_t)(i0 + ty * 2 + 0) * NN + j0 + tx * 2] = make_float2(c00, c01);
  *(float2*)&dot[(size_t)(i0 + ty * 2 + 1) * NN + j0 + tx * 2] = make_float2(c10, c11);

  float swv = sigw[0];
  float sp = (swv > 20.f) ? swv : log1pf(__expf(swv));
  float dotv[2][2] = {{c00, c01}, {c10, c11}};
#pragma unroll
  for (int r = 0; r < 2; r++) {
#pragma unroll
    for (int c = 0; c < 2; c++) {
      float d01 = x0nS[ty * 2 + r] + x1nS[tx * 2 + c] - 2.f * dotv[r][c];
      float ss = fmaf(sp, sqrtf(fmaxf(d01, 0.f) * (1.f / 128.f)), MIN_SIGMA);
      float Q = -0.72134752044f / (ss * ss);
      float R = -128.f * __log2f(ss);
      QPRS[ty * 2 + r][tx * 2 + c] = make_float4(Q, dotv[r][c] * Q, R, 0.f);
    }
  }
  __syncthreads();

  int b = tid & 31, rep = tid >> 5;
  float c2b = ws[OFF_C2 + b];
  float bpreg[32];
#pragma unroll
  for (int j = 0; j < 32; j++) bpreg[j] = BpT[j][b];
  float m = -3.4e38f;
#pragma unroll
  for (int r = 0; r < 4; r++) {
    int i = rep * 4 + r;
    float ap = ApT[i][b];
#pragma unroll
    for (int j = 0; j < 32; j++) {
      float4 q4 = QPRS[i][j];
      float core = fmaf(ap + bpreg[j], q4.x, fmaf(c2b, q4.y, q4.z));
      m = fmaxf(m, core);
    }
  }
  atomicMax(&mS[b], fkey(m));
  __syncthreads();
  if (tid < 32) atomicMax((unsigned*)ws + OFF_MAXKEY + tid, mS[tid]);
}

__global__ __launch_bounds__(256) void k2(const float* __restrict__ sigw,
                                          float* __restrict__ ws) {
  __shared__ __align__(16) float4 QPRS[32][32];
  __shared__ float ApT[32][33], BpT[32][33];
  __shared__ float colS[32][33], rowS[32][33];
  __shared__ float x0nS[32], x1nS[32];
  __shared__ float denS[32];

  int tid = threadIdx.x;
  int tx = tid & 15, ty = tid >> 4;
  int i0 = blockIdx.y * 32, j0 = blockIdx.x * 32;

  {
    const float* Ap = ws + OFF_AP;
    const float* Bp = ws + OFF_BP;
#pragma unroll
    for (int rep = 0; rep < 4; rep++) {
      int idx = rep * 256 + tid;
      int bb = idx >> 5, ii = idx & 31;
      ApT[ii][bb] = Ap[(size_t)bb * NN + i0 + ii];
      BpT[ii][bb] = Bp[(size_t)bb * NN + j0 + ii];
      colS[ii][bb] = 0.f;
    }
    if (tid < 32) {
      x0nS[tid] = ws[OFF_X0N + i0 + tid];
      x1nS[tid] = ws[OFF_X1N + j0 + tid];
      denS[tid] = 0.f;
    }
  }

  const float* dot = ws + OFF_DOT;
  float2 dv0 = *(const float2*)&dot[(size_t)(i0 + ty * 2 + 0) * NN + j0 + tx * 2];
  float2 dv1 = *(const float2*)&dot[(size_t)(i0 + ty * 2 + 1) * NN + j0 + tx * 2];
  float dotv[2][2] = {{dv0.x, dv0.y}, {dv1.x, dv1.y}};
  float swv = sigw[0];
  float sp = (swv > 20.f) ? swv : log1pf(__expf(swv));

  __syncthreads();

#pragma unroll
  for (int r = 0; r < 2; r++) {
#pragma unroll
    for (int c = 0; c < 2; c++) {
      float d01 = x0nS[ty * 2 + r] + x1nS[tx * 2 + c] - 2.f * dotv[r][c];
      float ss = fmaf(sp, sqrtf(fmaxf(d01, 0.f) * (1.f / 128.f)), MIN_SIGMA);
      float Q = -0.72134752044f / (ss * ss);
      float R = -128.f * __log2f(ss);
      QPRS[ty * 2 + r][tx * 2 + c] = make_float4(Q, dotv[r][c] * Q, R, 0.f);
    }
  }
  __syncthreads();

  int b = tid & 31, rep = tid >> 5;
  float c2b = ws[OFF_C2 + b];
  float m2 = funkey(((const unsigned*)ws)[OFF_MAXKEY + b]);
  float bpreg[32];
#pragma unroll
  for (int j = 0; j < 32; j++) bpreg[j] = BpT[j][b];
  float colreg[32];
#pragma unroll
  for (int j = 0; j < 32; j++) colreg[j] = 0.f;
  float dreg = 0.f;
#pragma unroll
  for (int r = 0; r < 4; r++) {
    int i = rep * 4 + r;
    float ap = ApT[i][b];
    float rs = 0.f;
#pragma unroll
    for (int j = 0; j < 32; j++) {
      float4 q4 = QPRS[i][j];
      float core = fmaf(ap + bpreg[j], q4.x, fmaf(c2b, q4.y, q4.z));
      float w = exp2f(core - m2);
      rs += w;
      colreg[j] += w;
    }
    rowS[i][b] = rs;
    dreg += rs;
  }
#pragma unroll
  for (int j = 0; j < 32; j++) atomicAdd(&colS[j][b], colreg[j]);
  atomicAdd(&denS[b], dreg);
  __syncthreads();

  float* rw = ws + OFF_RW;
  float* cw = ws + OFF_CW;
#pragma unroll
  for (int k = 0; k < 4; k++) {
    int idx = k * 256 + tid;
    int bb = idx >> 5, ii = idx & 31;
    atomicAdd(&rw[(size_t)bb * NN + i0 + ii], rowS[ii][bb]);
    atomicAdd(&cw[(size_t)bb * NN + j0 + ii], colS[ii][bb]);
  }
  if (tid < 32) atomicAdd(ws + OFF_DEN + tid, denS[tid]);
}

// ---------------- k3: weighted combine (grid 512 = b x 16 strips) ----
__global__ __launch_bounds__(256) void k3(const float* __restrict__ xt,
                                          const float* __restrict__ tarr,
                                          const float* __restrict__ x0,
                                          const float* __restrict__ x1,
                                          const float* __restrict__ ws,
                                          float* __restrict__ out) {
  __shared__ float s0[32][8], s1[32][8];
  int b = blockIdx.x >> 4, strip = blockIdx.x & 15;
  int tid = threadIdx.x;
  int c = tid & 7, h = tid >> 3;  // h in 0..31, 32 rows each
  int d = strip * 8 + c;
  const float* rw = ws + OFF_RW + (size_t)b * NN;
  const float* cw = ws + OFF_CW + (size_t)b * NN;
  float a0 = 0.f, a1 = 0.f;
#pragma unroll 4
  for (int k = 0; k < 32; k++) {
    int i = h * 32 + k;
    a0 = fmaf(rw[i], x0[(size_t)i * ND + d], a0);
    a1 = fmaf(cw[i], x1[(size_t)i * ND + d], a1);
  }
  s0[h][c] = a0;
  s1[h][c] = a1;
  __syncthreads();
  for (int s = 16; s > 0; s >>= 1) {
    if (h < s) {
      s0[h][c] += s0[h + s][c];
      s1[h][c] += s1[h + s][c];
    }
    __syncthreads();
  }
  if (h == 0) {
    float tb = tarr[b];
    float den = ws[OFF_DEN + b];
    float ct = (1.f - 2.f * tb) / (2.f * (tb + ETA) * (1.f - tb + ETA));
    float av = -1.f - ct * (1.f - tb);
    float bv = 1.f - ct * tb;
    float den_c = fmaxf(den, 1e-12f);
    out[(size_t)b * ND + d] =
        (ct * xt[(size_t)b * ND + d] * den + av * s0[0][c] + bv * s1[0][c]) / den_c;
  }
}

extern "C" void kernel_launch(void* const* d_in, const int* in_sizes, int n_in,
                              void* d_out, int out_size, void* d_ws, size_t ws_size,
                              hipStream_t stream) {
  const float* xt = (const float*)d_in[0];
  const float* t = (const float*)d_in[1];
  const float* x0 = (const float*)d_in[2];
  const float* x1 = (const float*)d_in[3];
  const float* sw = (const float*)d_in[4];
  float* out = (float*)d_out;
  float* ws = (float*)d_ws;

  bool fused = ws_size >= WS_NEED_FUSED * sizeof(float);

  if (fused) {
    hipMemsetAsync(ws, 0, 64 * sizeof(float), stream);  // den (+spare)
    k_ab<<<1024, 256, 0, stream>>>(xt, t, x0, x1, ws);
    kF<<<dim3(32, 32), 512, 0, stream>>>(x0, x1, sw, ws);
    kR<<<128, 256, 0, stream>>>(ws);
  } else {
    hipMemsetAsync(ws, 0, OFF_X0N * sizeof(float), stream);
    k_ab<<<1024, 256, 0, stream>>>(xt, t, x0, x1, ws);
    k1<<<dim3(32, 32), 256, 0, stream>>>(x0, x1, sw, ws);
    k2<<<dim3(32, 32), 256, 0, stream>>>(sw, ws);
  }
  k3<<<512, 256, 0, stream>>>(xt, t, x0, x1, ws, out);
}